// Round 11
// baseline (179.787 us; speedup 1.0000x reference)
//
#include <hip/hip_runtime.h>

typedef __attribute__((ext_vector_type(4))) float     floatx4;
typedef __attribute__((ext_vector_type(8))) _Float16  f16x8;
typedef __attribute__((ext_vector_type(4))) _Float16  f16x4;

#define NB    4096      // triple batch size
#define DIM   128
#define SLEN  10
#define CN0   20000
#define CN1   2000
#define CN2   15000
#define T1PAD 2048      // padded type-1 table size
#define GMT   16        // nodes per block in rnn kernel
#define XSTR  136       // LDS f16 row stride: 16B-aligned, bank-staggered rows

// ---------------- ws layout (bytes) ----------------
// he0 | he1 | he2 | hwih | hwhh | agg0 | agg1 | tbl1
static constexpr size_t OFF_HE0  = 0;
static constexpr size_t SZ_HE0   = (size_t)CN0 * DIM * 2;
static constexpr size_t OFF_HE1  = OFF_HE0 + SZ_HE0;
static constexpr size_t SZ_HE1   = (size_t)CN1 * DIM * 2;
static constexpr size_t OFF_HE2  = OFF_HE1 + SZ_HE1;
static constexpr size_t SZ_HE2   = (size_t)CN2 * DIM * 2;
static constexpr size_t OFF_WIH  = OFF_HE2 + SZ_HE2;
static constexpr size_t SZ_W     = (size_t)2 * 3 * DIM * DIM * 2;
static constexpr size_t OFF_WHH  = OFF_WIH + SZ_W;
static constexpr size_t OFF_AGG0 = OFF_WHH + SZ_W;
static constexpr size_t SZ_AGG0  = (size_t)6 * NB * DIM * 4;
static constexpr size_t OFF_AGG1 = OFF_AGG0 + SZ_AGG0;
static constexpr size_t SZ_AGG1  = (size_t)6 * T1PAD * DIM * 4;
static constexpr size_t OFF_TBL1 = OFF_AGG1 + SZ_AGG1;

__device__ __forceinline__ float fast_tanh(float x) {
    // 1 - 2/(e^{2x}+1): saturates cleanly at +/-inf (rcp(inf)=0, rcp(1)=1)
    float e = __expf(2.0f * x);
    return 1.0f - 2.0f * __builtin_amdgcn_rcpf(e + 1.0f);
}

// ---------------- prep: fp32 -> fp16 for embeddings + RNN weights ----------------
__global__ __launch_bounds__(256) void prep_kernel(
    const float* __restrict__ e0, const float* __restrict__ e1, const float* __restrict__ e2,
    const float* __restrict__ wih, const float* __restrict__ whh,
    _Float16* __restrict__ h0, _Float16* __restrict__ h1, _Float16* __restrict__ h2,
    _Float16* __restrict__ hwih, _Float16* __restrict__ hwhh)
{
    int i = blockIdx.x * 256 + threadIdx.x;   // in float4 units
    const int n0 = CN0 * DIM / 4, n1 = CN1 * DIM / 4, n2 = CN2 * DIM / 4;
    const int nw = 2 * 3 * DIM * DIM / 4;
    const float* src; _Float16* dst;
    if (i < n0)              { src = e0;  dst = h0;   }
    else if ((i -= n0) < n1) { src = e1;  dst = h1;   }
    else if ((i -= n1) < n2) { src = e2;  dst = h2;   }
    else if ((i -= n2) < nw) { src = wih; dst = hwih; }
    else if ((i -= nw) < nw) { src = whh; dst = hwhh; }
    else return;
    floatx4 v = ((const floatx4*)src)[i];
    f16x4 o = { (_Float16)v[0], (_Float16)v[1], (_Float16)v[2], (_Float16)v[3] };
    ((f16x4*)dst)[i] = o;
}

// ---------------- RNN-mean aggregation: both layers fused, 8 col-split waves ----------------
// Layers l=0,1 for the same (group,nt) read the SAME x rows -> stage once,
// run both layers' independent recurrences in one barrier group (r10 idea).
// r10 failed on register pressure (WRITE_SIZE 90 MB = spill at (512,4)'s
// 128-reg budget). Fix: ONE fb[4] fragment buffer reused for x then h
// (sequential use -> allocator renames, peak live ~119 <= 128). Weight slice
// stays 64 VGPRs/wave (r9-proven resident).
// Block = 512 threads = 8 waves, 16 nodes. Wave w: layer = w>>2, cols
// [32*(w&3), +32). Barriers drain LDS only (no vmem in the loop — r8-proven).
// Transposed-output MFMA: D'[n][node] = sum_k W[n][k] * X[node][k].
__global__ __launch_bounds__(512, 4) void rnn_kernel(
    const int* __restrict__ c_ids,
    const int* __restrict__ nb00, const int* __restrict__ nb01, const int* __restrict__ nb02,
    const int* __restrict__ nb10, const int* __restrict__ nb11, const int* __restrict__ nb12,
    const _Float16* __restrict__ he0, const _Float16* __restrict__ he1, const _Float16* __restrict__ he2,
    const _Float16* __restrict__ hwih, const _Float16* __restrict__ hwhh,
    const float* __restrict__ bih, const float* __restrict__ bhh,
    float* __restrict__ agg0, float* __restrict__ agg1)
{
    const int nt = blockIdx.y;           // 0..2
    int tile = blockIdx.x;
    int group, nodeBase;
    const int* neighTab;
    if (tile < NB / GMT) {
        group = 0; nodeBase = tile * GMT;
        neighTab = (nt == 0) ? nb00 : (nt == 1) ? nb01 : nb02;
    } else {
        group = 1; tile -= NB / GMT; nodeBase = tile * GMT;
        neighTab = (nt == 0) ? nb10 : (nt == 1) ? nb11 : nb12;
    }
    const _Float16* emb = (nt == 0) ? he0 : (nt == 1) ? he1 : he2;

    __shared__ int      sNid[GMT][SLEN];
    __shared__ _Float16 sX[SLEN * GMT * XSTR];   // 43520 B (shared by both layers)
    __shared__ _Float16 sH[2][2][GMT * XSTR];    // [layer][buf] 17408 B

    const int tid   = threadIdx.x;
    const int wave  = tid >> 6;          // 0..7
    const int layer = wave >> 2;         // 0..1
    const int colw  = wave & 3;          // owns cols [32*colw, 32*colw+32)
    const int lane  = tid & 63;
    const int quad  = lane >> 4;         // 0..3
    const int l16   = lane & 15;

    for (int i = tid; i < GMT * SLEN; i += 512) {
        int n = i / SLEN, s = i - n * SLEN;
        int node = nodeBase + n;
        int id = (group == 0) ? c_ids[node] : min(node, CN1 - 1);
        sNid[n][s] = neighTab[(size_t)id * SLEN + s];
    }
    __syncthreads();

    // Stage ALL x rows into LDS once for BOTH layers: 160 rows x 16 chunks of
    // 16B, coalesced (16 consecutive threads read one 256B row).
    for (int i = tid; i < GMT * SLEN * 16; i += 512) {
        int c  = i & 15;
        int rs = i >> 4;
        int n  = rs / SLEN, s = rs - n * SLEN;
        int nid = sNid[n][s];
        f16x8 v = *(const f16x8*)(emb + (size_t)nid * DIM + c * 8);
        *(f16x8*)(&sX[(s * GMT + n) * XSTR + c * 8]) = v;
    }

    // This wave's weight slice: rows [colw*32, colw*32+32) of its layer's Wih/Whh.
    const int lnt = layer * 3 + nt;
    const _Float16* Wih = hwih + (size_t)lnt * DIM * DIM;
    const _Float16* Whh = hwhh + (size_t)lnt * DIM * DIM;
    f16x8 wihR[2][4], whhR[2][4];        // 64 VGPRs — r9-proven resident
    #pragma unroll
    for (int a = 0; a < 2; a++) {
        int row = colw * 32 + a * 16 + l16;
        #pragma unroll
        for (int ks = 0; ks < 4; ks++) {
            int off = row * DIM + ks * 32 + quad * 8;
            wihR[a][ks] = *(const f16x8*)(Wih + off);
            whhR[a][ks] = *(const f16x8*)(Whh + off);
        }
    }
    floatx4 biasv[2];
    #pragma unroll
    for (int a = 0; a < 2; a++) {
        int n0 = colw * 32 + a * 16 + quad * 4;
        biasv[a] = *(const floatx4*)(bih + lnt * DIM + n0)
                 + *(const floatx4*)(bhh + lnt * DIM + n0);
    }
    floatx4 hsum[2];
    #pragma unroll
    for (int a = 0; a < 2; a++) hsum[a] = (floatx4)0.f;

    __syncthreads();   // staging complete; no vmem outstanding past this point

    for (int s = 0; s < SLEN; s++) {
        floatx4 acc[2];
        #pragma unroll
        for (int a = 0; a < 2; a++) acc[a] = biasv[a];

        // ONE fragment buffer, reused x-then-h: halves peak frag pressure
        f16x8 fb[4];
        const _Float16* xrow = &sX[(s * GMT + l16) * XSTR];
        #pragma unroll
        for (int ks = 0; ks < 4; ks++)
            fb[ks] = *(const f16x8*)(xrow + ks * 32 + quad * 8);
        #pragma unroll
        for (int ks = 0; ks < 4; ks++)
            #pragma unroll
            for (int a = 0; a < 2; a++)
                acc[a] = __builtin_amdgcn_mfma_f32_16x16x32_f16(wihR[a][ks], fb[ks], acc[a], 0, 0, 0);
        if (s > 0) {
            const _Float16* hrow = &sH[layer][(s + 1) & 1][l16 * XSTR];
            #pragma unroll
            for (int ks = 0; ks < 4; ks++)
                fb[ks] = *(const f16x8*)(hrow + ks * 32 + quad * 8);
            #pragma unroll
            for (int ks = 0; ks < 4; ks++)
                #pragma unroll
                for (int a = 0; a < 2; a++)
                    acc[a] = __builtin_amdgcn_mfma_f32_16x16x32_f16(whhR[a][ks], fb[ks], acc[a], 0, 0, 0);
        }
        #pragma unroll
        for (int a = 0; a < 2; a++) {
            float h0 = fast_tanh(acc[a][0]);
            float h1 = fast_tanh(acc[a][1]);
            float h2 = fast_tanh(acc[a][2]);
            float h3 = fast_tanh(acc[a][3]);
            hsum[a] += (floatx4){h0, h1, h2, h3};
            f16x4 hq = { (_Float16)h0, (_Float16)h1, (_Float16)h2, (_Float16)h3 };
            int n0 = colw * 32 + a * 16 + quad * 4;
            *(f16x4*)(&sH[layer][s & 1][l16 * XSTR + n0]) = hq;  // ds_write_b64
        }
        __syncthreads();   // drains LDS only — no vmem in flight
    }

    // agg = mean of 10 states
    const int lnt2 = layer * 3 + nt;
    float* aggOut = (group == 0) ? (agg0 + (size_t)lnt2 * NB * DIM + (size_t)(nodeBase + l16) * DIM)
                                 : (agg1 + (size_t)lnt2 * T1PAD * DIM + (size_t)(nodeBase + l16) * DIM);
    #pragma unroll
    for (int a = 0; a < 2; a++) {
        int n0 = colw * 32 + a * 16 + quad * 4;
        *(floatx4*)(aggOut + n0) = hsum[a] * 0.1f;
    }
}

// ---------------- attention combine (per node, one wave) ----------------
__device__ __forceinline__ float wsum64(float v) {
    #pragma unroll
    for (int off = 32; off > 0; off >>= 1) v += __shfl_xor(v, off, 64);
    return v;
}

__global__ __launch_bounds__(256) void att_kernel(
    const int* __restrict__ c_ids,
    const float* __restrict__ emb0, const float* __restrict__ emb1,
    const float* __restrict__ attW,
    const float* __restrict__ agg0, const float* __restrict__ agg1,
    float* __restrict__ outc, float* __restrict__ tbl1)
{
    const int wave = threadIdx.x >> 6, lane = threadIdx.x & 63;
    int gb = blockIdx.x;
    int group, node, Nn, ntype;
    const float* aggB; const float* emb;
    if (gb < NB / 4) { group = 0; node = gb * 4 + wave; ntype = 0; aggB = agg0; emb = emb0; Nn = NB; }
    else { group = 1; node = (gb - NB / 4) * 4 + wave; ntype = 1; aggB = agg1; emb = emb1; Nn = T1PAD; }
    int id = (group == 0) ? c_ids[node] : min(node, CN1 - 1);
    int d = lane * 2;
    float2 cur = *(const float2*)(emb + (size_t)id * DIM + d);

    #pragma unroll
    for (int l = 0; l < 2; l++) {
        float2 stk[3];
        #pragma unroll
        for (int k = 0; k < 3; k++)
            stk[k] = *(const float2*)(aggB + ((size_t)(l * 3 + k) * Nn + node) * DIM + d);
        const float* aw = attW + (l * 3 + ntype) * 2 * DIM;
        float2 ac = *(const float2*)(aw + d);
        float2 as = *(const float2*)(aw + DIM + d);
        float pc = ac.x * cur.x + ac.y * cur.y;
        float p0 = as.x * cur.x + as.y * cur.y;
        float p1 = as.x * stk[0].x + as.y * stk[0].y;
        float p2 = as.x * stk[1].x + as.y * stk[1].y;
        float p3 = as.x * stk[2].x + as.y * stk[2].y;
        float base = wsum64(pc);
        float s0 = base + wsum64(p0);
        float s1 = base + wsum64(p1);
        float s2 = base + wsum64(p2);
        float s3 = base + wsum64(p3);
        float mx = fmaxf(fmaxf(s0, s1), fmaxf(s2, s3));
        float e0 = __expf(s0 - mx), e1 = __expf(s1 - mx);
        float e2 = __expf(s2 - mx), e3 = __expf(s3 - mx);
        float rs = __builtin_amdgcn_rcpf(e0 + e1 + e2 + e3);
        float w0 = e0 * rs, w1 = e1 * rs, w2 = e2 * rs, w3 = e3 * rs;
        float nx = w0 * cur.x + w1 * stk[0].x + w2 * stk[1].x + w3 * stk[2].x;
        float ny = w0 * cur.y + w1 * stk[0].y + w2 * stk[1].y + w3 * stk[2].y;
        cur.x = nx > 0.f ? nx : 0.01f * nx;
        cur.y = ny > 0.f ? ny : 0.01f * ny;
    }
    float* dst = (group == 0) ? (outc + (size_t)node * DIM + d) : (tbl1 + (size_t)node * DIM + d);
    *(float2*)dst = cur;
}

// ---------------- gather pos/neg outputs from type-1 table ----------------
__global__ __launch_bounds__(256) void gather_kernel(
    const int* __restrict__ pos_ids, const int* __restrict__ neg_ids,
    const float* __restrict__ tbl1, float* __restrict__ outp, float* __restrict__ outn)
{
    int i = blockIdx.x * 256 + threadIdx.x;   // over 2 * NB * 32 float4s
    const int half = NB * 32;
    const int* ids; float* dst; int j = i;
    if (i < half) { ids = pos_ids; dst = outp; }
    else          { ids = neg_ids; dst = outn; j -= half; }
    int b = j >> 5, c = j & 31;
    int id = ids[b];
    ((floatx4*)dst)[j] = ((const floatx4*)tbl1)[(size_t)id * 32 + c];
}

extern "C" void kernel_launch(void* const* d_in, const int* in_sizes, int n_in,
                              void* d_out, int out_size, void* d_ws, size_t ws_size,
                              hipStream_t stream)
{
    const int* c_ids   = (const int*)d_in[0];
    const int* pos_ids = (const int*)d_in[1];
    const int* neg_ids = (const int*)d_in[2];
    const int* nb00 = (const int*)d_in[3];
    const int* nb01 = (const int*)d_in[4];
    const int* nb02 = (const int*)d_in[5];
    const int* nb10 = (const int*)d_in[6];
    const int* nb11 = (const int*)d_in[7];
    const int* nb12 = (const int*)d_in[8];
    const float* emb0 = (const float*)d_in[12];
    const float* emb1 = (const float*)d_in[13];
    const float* emb2 = (const float*)d_in[14];
    const float* rWih = (const float*)d_in[15];
    const float* rWhh = (const float*)d_in[16];
    const float* rbih = (const float*)d_in[17];
    const float* rbhh = (const float*)d_in[18];
    const float* attW = (const float*)d_in[19];

    char* ws = (char*)d_ws;
    _Float16* he0  = (_Float16*)(ws + OFF_HE0);
    _Float16* he1  = (_Float16*)(ws + OFF_HE1);
    _Float16* he2  = (_Float16*)(ws + OFF_HE2);
    _Float16* hwih = (_Float16*)(ws + OFF_WIH);
    _Float16* hwhh = (_Float16*)(ws + OFF_WHH);
    float*    agg0 = (float*)(ws + OFF_AGG0);
    float*    agg1 = (float*)(ws + OFF_AGG1);
    float*    tbl1 = (float*)(ws + OFF_TBL1);

    float* out  = (float*)d_out;
    float* outc = out;
    float* outp = out + (size_t)NB * DIM;
    float* outn = out + (size_t)2 * NB * DIM;

    // 1) fp16 conversion of embeddings + weights
    {
        int total4 = (CN0 + CN1 + CN2) * DIM / 4 + 2 * (2 * 3 * DIM * DIM / 4);
        int blocks = (total4 + 255) / 256;
        prep_kernel<<<blocks, 256, 0, stream>>>(emb0, emb1, emb2, rWih, rWhh,
                                                he0, he1, he2, hwih, hwhh);
    }
    // 2) RNN-mean aggregations: both layers fused; c batch + full type-1 table
    {
        dim3 grid(NB / GMT + T1PAD / GMT, 3);
        rnn_kernel<<<grid, 512, 0, stream>>>(c_ids, nb00, nb01, nb02, nb10, nb11, nb12,
                                             he0, he1, he2, hwih, hwhh, rbih, rbhh,
                                             agg0, agg1);
    }
    // 3) attention combine
    {
        int blocks = NB / 4 + T1PAD / 4;
        att_kernel<<<blocks, 256, 0, stream>>>(c_ids, emb0, emb1, attW, agg0, agg1,
                                               outc, tbl1);
    }
    // 4) gather pos/neg outputs
    {
        int blocks = 2 * NB * 32 / 256;
        gather_kernel<<<blocks, 256, 0, stream>>>(pos_ids, neg_ids, tbl1, outp, outn);
    }
}

// Round 12
// 174.327 us; speedup vs baseline: 1.0313x; 1.0313x over previous
//
#include <hip/hip_runtime.h>

typedef __attribute__((ext_vector_type(4))) float     floatx4;
typedef __attribute__((ext_vector_type(8))) _Float16  f16x8;
typedef __attribute__((ext_vector_type(4))) _Float16  f16x4;

#define NB    4096      // triple batch size
#define DIM   128
#define SLEN  10
#define CN0   20000
#define CN1   2000
#define CN2   15000
#define T1PAD 2048      // padded type-1 table size
#define GMT   16        // nodes per block in rnn kernel
#define XSTR  136       // LDS f16 row stride: 16B-aligned, bank-staggered rows

// ---------------- ws layout (bytes) ----------------
// he0 | he1 | he2 | hwih | hwhh | agg0 | agg1 | tbl1
static constexpr size_t OFF_HE0  = 0;
static constexpr size_t SZ_HE0   = (size_t)CN0 * DIM * 2;
static constexpr size_t OFF_HE1  = OFF_HE0 + SZ_HE0;
static constexpr size_t SZ_HE1   = (size_t)CN1 * DIM * 2;
static constexpr size_t OFF_HE2  = OFF_HE1 + SZ_HE1;
static constexpr size_t SZ_HE2   = (size_t)CN2 * DIM * 2;
static constexpr size_t OFF_WIH  = OFF_HE2 + SZ_HE2;
static constexpr size_t SZ_W     = (size_t)2 * 3 * DIM * DIM * 2;
static constexpr size_t OFF_WHH  = OFF_WIH + SZ_W;
static constexpr size_t OFF_AGG0 = OFF_WHH + SZ_W;
static constexpr size_t SZ_AGG0  = (size_t)6 * NB * DIM * 4;
static constexpr size_t OFF_AGG1 = OFF_AGG0 + SZ_AGG0;
static constexpr size_t SZ_AGG1  = (size_t)6 * T1PAD * DIM * 4;
static constexpr size_t OFF_TBL1 = OFF_AGG1 + SZ_AGG1;

__device__ __forceinline__ float fast_tanh(float x) {
    // 1 - 2/(e^{2x}+1): saturates cleanly at +/-inf (rcp(inf)=0, rcp(1)=1)
    float e = __expf(2.0f * x);
    return 1.0f - 2.0f * __builtin_amdgcn_rcpf(e + 1.0f);
}

// ---------------- prep: fp32 -> fp16 for embeddings + RNN weights ----------------
__global__ __launch_bounds__(256) void prep_kernel(
    const float* __restrict__ e0, const float* __restrict__ e1, const float* __restrict__ e2,
    const float* __restrict__ wih, const float* __restrict__ whh,
    _Float16* __restrict__ h0, _Float16* __restrict__ h1, _Float16* __restrict__ h2,
    _Float16* __restrict__ hwih, _Float16* __restrict__ hwhh)
{
    int i = blockIdx.x * 256 + threadIdx.x;   // in float4 units
    const int n0 = CN0 * DIM / 4, n1 = CN1 * DIM / 4, n2 = CN2 * DIM / 4;
    const int nw = 2 * 3 * DIM * DIM / 4;
    const float* src; _Float16* dst;
    if (i < n0)              { src = e0;  dst = h0;   }
    else if ((i -= n0) < n1) { src = e1;  dst = h1;   }
    else if ((i -= n1) < n2) { src = e2;  dst = h2;   }
    else if ((i -= n2) < nw) { src = wih; dst = hwih; }
    else if ((i -= nw) < nw) { src = whh; dst = hwhh; }
    else return;
    floatx4 v = ((const floatx4*)src)[i];
    f16x4 o = { (_Float16)v[0], (_Float16)v[1], (_Float16)v[2], (_Float16)v[3] };
    ((f16x4*)dst)[i] = o;
}

// ---------------- RNN-mean aggregation: both layers fused, 8 col-split waves ----------------
// Layers l=0,1 for the same (group,nt) read the SAME x rows -> stage once,
// run both layers' independent recurrences in one barrier group.
// r10/r11 failed on register pressure: (512,4)'s 128-reg budget forces a
// 64-VGPR arch split and spills ~70 MB to scratch (WRITE_SIZE 90 MB, twice).
// Fix: __launch_bounds__(512,2) -> 256-reg budget (r9-proven: body uses ~80,
// zero spill). Residency is then LDS-limited: 62 KB/block -> 2 blocks/CU =
// 16 waves/CU (2x r9's TLP).
// Block = 512 threads = 8 waves, 16 nodes. Wave w: layer = w>>2, cols
// [32*(w&3), +32) -> weight slice = 64 VGPRs/wave (r9-proven resident).
// ALL x staged to LDS pre-loop; per-step barriers drain LDS only (r8-proven).
// Transposed-output MFMA: D'[n][node] = sum_k W[n][k] * X[node][k].
__global__ __launch_bounds__(512, 2) void rnn_kernel(
    const int* __restrict__ c_ids,
    const int* __restrict__ nb00, const int* __restrict__ nb01, const int* __restrict__ nb02,
    const int* __restrict__ nb10, const int* __restrict__ nb11, const int* __restrict__ nb12,
    const _Float16* __restrict__ he0, const _Float16* __restrict__ he1, const _Float16* __restrict__ he2,
    const _Float16* __restrict__ hwih, const _Float16* __restrict__ hwhh,
    const float* __restrict__ bih, const float* __restrict__ bhh,
    float* __restrict__ agg0, float* __restrict__ agg1)
{
    const int nt = blockIdx.y;           // 0..2
    int tile = blockIdx.x;
    int group, nodeBase;
    const int* neighTab;
    if (tile < NB / GMT) {
        group = 0; nodeBase = tile * GMT;
        neighTab = (nt == 0) ? nb00 : (nt == 1) ? nb01 : nb02;
    } else {
        group = 1; tile -= NB / GMT; nodeBase = tile * GMT;
        neighTab = (nt == 0) ? nb10 : (nt == 1) ? nb11 : nb12;
    }
    const _Float16* emb = (nt == 0) ? he0 : (nt == 1) ? he1 : he2;

    __shared__ int      sNid[GMT][SLEN];
    __shared__ _Float16 sX[SLEN * GMT * XSTR];   // 43520 B (shared by both layers)
    __shared__ _Float16 sH[2][2][GMT * XSTR];    // [layer][buf] 17408 B

    const int tid   = threadIdx.x;
    const int wave  = tid >> 6;          // 0..7
    const int layer = wave >> 2;         // 0..1
    const int colw  = wave & 3;          // owns cols [32*colw, 32*colw+32)
    const int lane  = tid & 63;
    const int quad  = lane >> 4;         // 0..3
    const int l16   = lane & 15;

    for (int i = tid; i < GMT * SLEN; i += 512) {
        int n = i / SLEN, s = i - n * SLEN;
        int node = nodeBase + n;
        int id = (group == 0) ? c_ids[node] : min(node, CN1 - 1);
        sNid[n][s] = neighTab[(size_t)id * SLEN + s];
    }
    __syncthreads();

    // Stage ALL x rows into LDS once for BOTH layers: 160 rows x 16 chunks of
    // 16B, coalesced (16 consecutive threads read one 256B row).
    for (int i = tid; i < GMT * SLEN * 16; i += 512) {
        int c  = i & 15;
        int rs = i >> 4;
        int n  = rs / SLEN, s = rs - n * SLEN;
        int nid = sNid[n][s];
        f16x8 v = *(const f16x8*)(emb + (size_t)nid * DIM + c * 8);
        *(f16x8*)(&sX[(s * GMT + n) * XSTR + c * 8]) = v;
    }

    // This wave's weight slice: rows [colw*32, colw*32+32) of its layer's Wih/Whh.
    const int lnt = layer * 3 + nt;
    const _Float16* Wih = hwih + (size_t)lnt * DIM * DIM;
    const _Float16* Whh = hwhh + (size_t)lnt * DIM * DIM;
    f16x8 wihR[2][4], whhR[2][4];        // 64 VGPRs — r9-proven resident
    #pragma unroll
    for (int a = 0; a < 2; a++) {
        int row = colw * 32 + a * 16 + l16;
        #pragma unroll
        for (int ks = 0; ks < 4; ks++) {
            int off = row * DIM + ks * 32 + quad * 8;
            wihR[a][ks] = *(const f16x8*)(Wih + off);
            whhR[a][ks] = *(const f16x8*)(Whh + off);
        }
    }
    floatx4 biasv[2];
    #pragma unroll
    for (int a = 0; a < 2; a++) {
        int n0 = colw * 32 + a * 16 + quad * 4;
        biasv[a] = *(const floatx4*)(bih + lnt * DIM + n0)
                 + *(const floatx4*)(bhh + lnt * DIM + n0);
    }
    floatx4 hsum[2];
    #pragma unroll
    for (int a = 0; a < 2; a++) hsum[a] = (floatx4)0.f;

    __syncthreads();   // staging complete; no vmem outstanding past this point

    for (int s = 0; s < SLEN; s++) {
        floatx4 acc[2];
        #pragma unroll
        for (int a = 0; a < 2; a++) acc[a] = biasv[a];

        // ONE fragment buffer, reused x-then-h
        f16x8 fb[4];
        const _Float16* xrow = &sX[(s * GMT + l16) * XSTR];
        #pragma unroll
        for (int ks = 0; ks < 4; ks++)
            fb[ks] = *(const f16x8*)(xrow + ks * 32 + quad * 8);
        #pragma unroll
        for (int ks = 0; ks < 4; ks++)
            #pragma unroll
            for (int a = 0; a < 2; a++)
                acc[a] = __builtin_amdgcn_mfma_f32_16x16x32_f16(wihR[a][ks], fb[ks], acc[a], 0, 0, 0);
        if (s > 0) {
            const _Float16* hrow = &sH[layer][(s + 1) & 1][l16 * XSTR];
            #pragma unroll
            for (int ks = 0; ks < 4; ks++)
                fb[ks] = *(const f16x8*)(hrow + ks * 32 + quad * 8);
            #pragma unroll
            for (int ks = 0; ks < 4; ks++)
                #pragma unroll
                for (int a = 0; a < 2; a++)
                    acc[a] = __builtin_amdgcn_mfma_f32_16x16x32_f16(whhR[a][ks], fb[ks], acc[a], 0, 0, 0);
        }
        #pragma unroll
        for (int a = 0; a < 2; a++) {
            float h0 = fast_tanh(acc[a][0]);
            float h1 = fast_tanh(acc[a][1]);
            float h2 = fast_tanh(acc[a][2]);
            float h3 = fast_tanh(acc[a][3]);
            hsum[a] += (floatx4){h0, h1, h2, h3};
            f16x4 hq = { (_Float16)h0, (_Float16)h1, (_Float16)h2, (_Float16)h3 };
            int n0 = colw * 32 + a * 16 + quad * 4;
            *(f16x4*)(&sH[layer][s & 1][l16 * XSTR + n0]) = hq;  // ds_write_b64
        }
        __syncthreads();   // drains LDS only — no vmem in flight
    }

    // agg = mean of 10 states
    float* aggOut = (group == 0) ? (agg0 + (size_t)lnt * NB * DIM + (size_t)(nodeBase + l16) * DIM)
                                 : (agg1 + (size_t)lnt * T1PAD * DIM + (size_t)(nodeBase + l16) * DIM);
    #pragma unroll
    for (int a = 0; a < 2; a++) {
        int n0 = colw * 32 + a * 16 + quad * 4;
        *(floatx4*)(aggOut + n0) = hsum[a] * 0.1f;
    }
}

// ---------------- attention combine (per node, one wave) ----------------
__device__ __forceinline__ float wsum64(float v) {
    #pragma unroll
    for (int off = 32; off > 0; off >>= 1) v += __shfl_xor(v, off, 64);
    return v;
}

__global__ __launch_bounds__(256) void att_kernel(
    const int* __restrict__ c_ids,
    const float* __restrict__ emb0, const float* __restrict__ emb1,
    const float* __restrict__ attW,
    const float* __restrict__ agg0, const float* __restrict__ agg1,
    float* __restrict__ outc, float* __restrict__ tbl1)
{
    const int wave = threadIdx.x >> 6, lane = threadIdx.x & 63;
    int gb = blockIdx.x;
    int group, node, Nn, ntype;
    const float* aggB; const float* emb;
    if (gb < NB / 4) { group = 0; node = gb * 4 + wave; ntype = 0; aggB = agg0; emb = emb0; Nn = NB; }
    else { group = 1; node = (gb - NB / 4) * 4 + wave; ntype = 1; aggB = agg1; emb = emb1; Nn = T1PAD; }
    int id = (group == 0) ? c_ids[node] : min(node, CN1 - 1);
    int d = lane * 2;
    float2 cur = *(const float2*)(emb + (size_t)id * DIM + d);

    #pragma unroll
    for (int l = 0; l < 2; l++) {
        float2 stk[3];
        #pragma unroll
        for (int k = 0; k < 3; k++)
            stk[k] = *(const float2*)(aggB + ((size_t)(l * 3 + k) * Nn + node) * DIM + d);
        const float* aw = attW + (l * 3 + ntype) * 2 * DIM;
        float2 ac = *(const float2*)(aw + d);
        float2 as = *(const float2*)(aw + DIM + d);
        float pc = ac.x * cur.x + ac.y * cur.y;
        float p0 = as.x * cur.x + as.y * cur.y;
        float p1 = as.x * stk[0].x + as.y * stk[0].y;
        float p2 = as.x * stk[1].x + as.y * stk[1].y;
        float p3 = as.x * stk[2].x + as.y * stk[2].y;
        float base = wsum64(pc);
        float s0 = base + wsum64(p0);
        float s1 = base + wsum64(p1);
        float s2 = base + wsum64(p2);
        float s3 = base + wsum64(p3);
        float mx = fmaxf(fmaxf(s0, s1), fmaxf(s2, s3));
        float e0 = __expf(s0 - mx), e1 = __expf(s1 - mx);
        float e2 = __expf(s2 - mx), e3 = __expf(s3 - mx);
        float rs = __builtin_amdgcn_rcpf(e0 + e1 + e2 + e3);
        float w0 = e0 * rs, w1 = e1 * rs, w2 = e2 * rs, w3 = e3 * rs;
        float nx = w0 * cur.x + w1 * stk[0].x + w2 * stk[1].x + w3 * stk[2].x;
        float ny = w0 * cur.y + w1 * stk[0].y + w2 * stk[1].y + w3 * stk[2].y;
        cur.x = nx > 0.f ? nx : 0.01f * nx;
        cur.y = ny > 0.f ? ny : 0.01f * ny;
    }
    float* dst = (group == 0) ? (outc + (size_t)node * DIM + d) : (tbl1 + (size_t)node * DIM + d);
    *(float2*)dst = cur;
}

// ---------------- gather pos/neg outputs from type-1 table ----------------
__global__ __launch_bounds__(256) void gather_kernel(
    const int* __restrict__ pos_ids, const int* __restrict__ neg_ids,
    const float* __restrict__ tbl1, float* __restrict__ outp, float* __restrict__ outn)
{
    int i = blockIdx.x * 256 + threadIdx.x;   // over 2 * NB * 32 float4s
    const int half = NB * 32;
    const int* ids; float* dst; int j = i;
    if (i < half) { ids = pos_ids; dst = outp; }
    else          { ids = neg_ids; dst = outn; j -= half; }
    int b = j >> 5, c = j & 31;
    int id = ids[b];
    ((floatx4*)dst)[j] = ((const floatx4*)tbl1)[(size_t)id * 32 + c];
}

extern "C" void kernel_launch(void* const* d_in, const int* in_sizes, int n_in,
                              void* d_out, int out_size, void* d_ws, size_t ws_size,
                              hipStream_t stream)
{
    const int* c_ids   = (const int*)d_in[0];
    const int* pos_ids = (const int*)d_in[1];
    const int* neg_ids = (const int*)d_in[2];
    const int* nb00 = (const int*)d_in[3];
    const int* nb01 = (const int*)d_in[4];
    const int* nb02 = (const int*)d_in[5];
    const int* nb10 = (const int*)d_in[6];
    const int* nb11 = (const int*)d_in[7];
    const int* nb12 = (const int*)d_in[8];
    const float* emb0 = (const float*)d_in[12];
    const float* emb1 = (const float*)d_in[13];
    const float* emb2 = (const float*)d_in[14];
    const float* rWih = (const float*)d_in[15];
    const float* rWhh = (const float*)d_in[16];
    const float* rbih = (const float*)d_in[17];
    const float* rbhh = (const float*)d_in[18];
    const float* attW = (const float*)d_in[19];

    char* ws = (char*)d_ws;
    _Float16* he0  = (_Float16*)(ws + OFF_HE0);
    _Float16* he1  = (_Float16*)(ws + OFF_HE1);
    _Float16* he2  = (_Float16*)(ws + OFF_HE2);
    _Float16* hwih = (_Float16*)(ws + OFF_WIH);
    _Float16* hwhh = (_Float16*)(ws + OFF_WHH);
    float*    agg0 = (float*)(ws + OFF_AGG0);
    float*    agg1 = (float*)(ws + OFF_AGG1);
    float*    tbl1 = (float*)(ws + OFF_TBL1);

    float* out  = (float*)d_out;
    float* outc = out;
    float* outp = out + (size_t)NB * DIM;
    float* outn = out + (size_t)2 * NB * DIM;

    // 1) fp16 conversion of embeddings + weights
    {
        int total4 = (CN0 + CN1 + CN2) * DIM / 4 + 2 * (2 * 3 * DIM * DIM / 4);
        int blocks = (total4 + 255) / 256;
        prep_kernel<<<blocks, 256, 0, stream>>>(emb0, emb1, emb2, rWih, rWhh,
                                                he0, he1, he2, hwih, hwhh);
    }
    // 2) RNN-mean aggregations: both layers fused; c batch + full type-1 table
    {
        dim3 grid(NB / GMT + T1PAD / GMT, 3);
        rnn_kernel<<<grid, 512, 0, stream>>>(c_ids, nb00, nb01, nb02, nb10, nb11, nb12,
                                             he0, he1, he2, hwih, hwhh, rbih, rbhh,
                                             agg0, agg1);
    }
    // 3) attention combine
    {
        int blocks = NB / 4 + T1PAD / 4;
        att_kernel<<<blocks, 256, 0, stream>>>(c_ids, emb0, emb1, attW, agg0, agg1,
                                               outc, tbl1);
    }
    // 4) gather pos/neg outputs
    {
        int blocks = 2 * NB * 32 / 256;
        gather_kernel<<<blocks, 256, 0, stream>>>(pos_ids, neg_ids, tbl1, outp, outn);
    }
}

// Round 13
// 158.791 us; speedup vs baseline: 1.1322x; 1.0978x over previous
//
#include <hip/hip_runtime.h>

typedef __attribute__((ext_vector_type(4))) float     floatx4;
typedef __attribute__((ext_vector_type(8))) _Float16  f16x8;
typedef __attribute__((ext_vector_type(4))) _Float16  f16x4;

#define NB    4096      // triple batch size
#define DIM   128
#define SLEN  10
#define CN0   20000
#define CN1   2000
#define CN2   15000
#define T1PAD 2048      // padded type-1 table size
#define GMT   16        // nodes per block in rnn kernel
#define XSTR  136       // LDS f16 row stride: 16B-aligned, bank-staggered rows
#define SSTG  (SLEN-1)  // steps staged in LDS (1..9); step 0 lives in registers

// ---------------- ws layout (bytes) ----------------
// he0 | he1 | he2 | hwih | hwhh | agg0 | agg1 | tbl1
static constexpr size_t OFF_HE0  = 0;
static constexpr size_t SZ_HE0   = (size_t)CN0 * DIM * 2;
static constexpr size_t OFF_HE1  = OFF_HE0 + SZ_HE0;
static constexpr size_t SZ_HE1   = (size_t)CN1 * DIM * 2;
static constexpr size_t OFF_HE2  = OFF_HE1 + SZ_HE1;
static constexpr size_t SZ_HE2   = (size_t)CN2 * DIM * 2;
static constexpr size_t OFF_WIH  = OFF_HE2 + SZ_HE2;
static constexpr size_t SZ_W     = (size_t)2 * 3 * DIM * DIM * 2;
static constexpr size_t OFF_WHH  = OFF_WIH + SZ_W;
static constexpr size_t OFF_AGG0 = OFF_WHH + SZ_W;
static constexpr size_t SZ_AGG0  = (size_t)6 * NB * DIM * 4;
static constexpr size_t OFF_AGG1 = OFF_AGG0 + SZ_AGG0;
static constexpr size_t SZ_AGG1  = (size_t)6 * T1PAD * DIM * 4;
static constexpr size_t OFF_TBL1 = OFF_AGG1 + SZ_AGG1;

__device__ __forceinline__ float fast_tanh(float x) {
    // 1 - 2/(e^{2x}+1): saturates cleanly at +/-inf (rcp(inf)=0, rcp(1)=1)
    float e = __expf(2.0f * x);
    return 1.0f - 2.0f * __builtin_amdgcn_rcpf(e + 1.0f);
}

// ---------------- prep: fp32 -> fp16 for embeddings + RNN weights ----------------
__global__ __launch_bounds__(256) void prep_kernel(
    const float* __restrict__ e0, const float* __restrict__ e1, const float* __restrict__ e2,
    const float* __restrict__ wih, const float* __restrict__ whh,
    _Float16* __restrict__ h0, _Float16* __restrict__ h1, _Float16* __restrict__ h2,
    _Float16* __restrict__ hwih, _Float16* __restrict__ hwhh)
{
    int i = blockIdx.x * 256 + threadIdx.x;   // in float4 units
    const int n0 = CN0 * DIM / 4, n1 = CN1 * DIM / 4, n2 = CN2 * DIM / 4;
    const int nw = 2 * 3 * DIM * DIM / 4;
    const float* src; _Float16* dst;
    if (i < n0)              { src = e0;  dst = h0;   }
    else if ((i -= n0) < n1) { src = e1;  dst = h1;   }
    else if ((i -= n1) < n2) { src = e2;  dst = h2;   }
    else if ((i -= n2) < nw) { src = wih; dst = hwih; }
    else if ((i -= nw) < nw) { src = whh; dst = hwhh; }
    else return;
    floatx4 v = ((const floatx4*)src)[i];
    f16x4 o = { (_Float16)v[0], (_Float16)v[1], (_Float16)v[2], (_Float16)v[3] };
    ((f16x4*)dst)[i] = o;
}

// ---------------- RNN-mean aggregation: 4 col-split waves, LDS-staged x ----------------
// r9 structure (best: 51.6 us, VGPR=80, zero spill) with two occupancy fixes:
//  1. sX stages only steps 1..9 (39,168 B); step-0 x is loaded straight into
//     registers during staging. LDS block drops 53,248 -> 48,512 B, under the
//     48 KB allocation granule -> 3 blocks/CU instead of 2 (r12 showed
//     blocks/CU = independent barrier groups is the controlling variable).
//  2. Next-step x is prefetched BEFORE the per-step barrier (sX is immutable
//     after staging, so the read needs no barrier) -> post-barrier critical
//     path is just the hb load.
// Block = 256 threads = 4 waves, 16 nodes. Wave w owns cols [32w, 32w+32)
// -> 64-VGPR weight slice (r9-proven resident). Barriers drain LDS only.
// Transposed-output MFMA: D'[n][node] = sum_k W[n][k] * X[node][k].
__global__ __launch_bounds__(256, 2) void rnn_kernel(
    const int* __restrict__ c_ids,
    const int* __restrict__ nb00, const int* __restrict__ nb01, const int* __restrict__ nb02,
    const int* __restrict__ nb10, const int* __restrict__ nb11, const int* __restrict__ nb12,
    const _Float16* __restrict__ he0, const _Float16* __restrict__ he1, const _Float16* __restrict__ he2,
    const _Float16* __restrict__ hwih, const _Float16* __restrict__ hwhh,
    const float* __restrict__ bih, const float* __restrict__ bhh,
    float* __restrict__ agg0, float* __restrict__ agg1)
{
    const int lnt = blockIdx.y;          // l*3 + nt
    const int nt  = lnt % 3;
    int tile = blockIdx.x;
    int group, nodeBase;
    float* aggOut;
    const int* neighTab;
    if (tile < NB / GMT) {
        group = 0; nodeBase = tile * GMT;
        neighTab = (nt == 0) ? nb00 : (nt == 1) ? nb01 : nb02;
        aggOut = agg0 + (size_t)lnt * NB * DIM;
    } else {
        group = 1; tile -= NB / GMT; nodeBase = tile * GMT;
        neighTab = (nt == 0) ? nb10 : (nt == 1) ? nb11 : nb12;
        aggOut = agg1 + (size_t)lnt * T1PAD * DIM;
    }
    const _Float16* emb = (nt == 0) ? he0 : (nt == 1) ? he1 : he2;

    __shared__ int      sNid[GMT][SLEN];
    __shared__ _Float16 sX[SSTG * GMT * XSTR];   // 39168 B (steps 1..9)
    __shared__ _Float16 sH[2][GMT * XSTR];       //  8704 B

    const int tid  = threadIdx.x;
    const int wave = tid >> 6;           // 0..3: owns cols [32w, 32w+32)
    const int lane = tid & 63;
    const int quad = lane >> 4;          // 0..3
    const int l16  = lane & 15;

    for (int i = tid; i < GMT * SLEN; i += 256) {
        int n = i / SLEN, s = i - n * SLEN;
        int node = nodeBase + n;
        int id = (group == 0) ? c_ids[node] : min(node, CN1 - 1);
        sNid[n][s] = neighTab[(size_t)id * SLEN + s];
    }
    __syncthreads();

    // Step-0 x straight into registers (per-lane gather, overlaps staging)
    f16x8 xb[4];
    {
        int nid0 = sNid[l16][0];
        const _Float16* xr = emb + (size_t)nid0 * DIM;
        #pragma unroll
        for (int ks = 0; ks < 4; ks++)
            xb[ks] = *(const f16x8*)(xr + ks * 32 + quad * 8);
    }

    // Stage x rows for steps 1..9 into LDS: 144 rows x 16 chunks of 16B,
    // coalesced (16 consecutive threads read one 256B row). Slot = step-1.
    for (int i = tid; i < GMT * SSTG * 16; i += 256) {
        int c  = i & 15;
        int rs = i >> 4;
        int n  = rs / SSTG, sl = rs - n * SSTG;   // sl = step-1
        int nid = sNid[n][sl + 1];
        f16x8 v = *(const f16x8*)(emb + (size_t)nid * DIM + c * 8);
        *(f16x8*)(&sX[(sl * GMT + n) * XSTR + c * 8]) = v;
    }

    // This wave's weight slice: rows [wave*32, wave*32+32) of Wih and Whh.
    const _Float16* Wih = hwih + (size_t)lnt * DIM * DIM;
    const _Float16* Whh = hwhh + (size_t)lnt * DIM * DIM;
    f16x8 wihR[2][4], whhR[2][4];        // 64 VGPRs — r9-proven resident
    #pragma unroll
    for (int a = 0; a < 2; a++) {
        int row = wave * 32 + a * 16 + l16;
        #pragma unroll
        for (int ks = 0; ks < 4; ks++) {
            int off = row * DIM + ks * 32 + quad * 8;
            wihR[a][ks] = *(const f16x8*)(Wih + off);
            whhR[a][ks] = *(const f16x8*)(Whh + off);
        }
    }
    floatx4 biasv[2];
    #pragma unroll
    for (int a = 0; a < 2; a++) {
        int n0 = wave * 32 + a * 16 + quad * 4;
        biasv[a] = *(const floatx4*)(bih + lnt * DIM + n0)
                 + *(const floatx4*)(bhh + lnt * DIM + n0);
    }
    floatx4 hsum[2];
    #pragma unroll
    for (int a = 0; a < 2; a++) hsum[a] = (floatx4)0.f;

    __syncthreads();   // staging complete; no vmem outstanding past this point

    for (int s = 0; s < SLEN; s++) {
        // h_{s-1} B-frags (post-barrier read — the only barrier-dependent load)
        f16x8 hb[4];
        if (s > 0) {
            const _Float16* hrow = &sH[(s + 1) & 1][l16 * XSTR];
            #pragma unroll
            for (int ks = 0; ks < 4; ks++)
                hb[ks] = *(const f16x8*)(hrow + ks * 32 + quad * 8);
        }
        // prefetch next step's x NOW (sX immutable -> barrier-independent).
        // Clamped slot on the last iteration avoids any uninitialized path.
        f16x8 xbn[4];
        {
            int sl = (s < SLEN - 1) ? s : (SLEN - 2);   // slot for step s+1
            const _Float16* xrow = &sX[(sl * GMT + l16) * XSTR];
            #pragma unroll
            for (int ks = 0; ks < 4; ks++)
                xbn[ks] = *(const f16x8*)(xrow + ks * 32 + quad * 8);
        }
        floatx4 acc[2];
        #pragma unroll
        for (int a = 0; a < 2; a++) acc[a] = biasv[a];
        #pragma unroll
        for (int ks = 0; ks < 4; ks++)
            #pragma unroll
            for (int a = 0; a < 2; a++)
                acc[a] = __builtin_amdgcn_mfma_f32_16x16x32_f16(wihR[a][ks], xb[ks], acc[a], 0, 0, 0);
        if (s > 0) {
            #pragma unroll
            for (int ks = 0; ks < 4; ks++)
                #pragma unroll
                for (int a = 0; a < 2; a++)
                    acc[a] = __builtin_amdgcn_mfma_f32_16x16x32_f16(whhR[a][ks], hb[ks], acc[a], 0, 0, 0);
        }
        #pragma unroll
        for (int a = 0; a < 2; a++) {
            float h0 = fast_tanh(acc[a][0]);
            float h1 = fast_tanh(acc[a][1]);
            float h2 = fast_tanh(acc[a][2]);
            float h3 = fast_tanh(acc[a][3]);
            hsum[a] += (floatx4){h0, h1, h2, h3};
            f16x4 hq = { (_Float16)h0, (_Float16)h1, (_Float16)h2, (_Float16)h3 };
            int n0 = wave * 32 + a * 16 + quad * 4;
            *(f16x4*)(&sH[s & 1][l16 * XSTR + n0]) = hq;   // ds_write_b64, own cols
        }
        __syncthreads();   // drains LDS only — no vmem in flight
        #pragma unroll
        for (int ks = 0; ks < 4; ks++) xb[ks] = xbn[ks];
    }

    // agg = mean of 10 states
    int node = nodeBase + l16;
    #pragma unroll
    for (int a = 0; a < 2; a++) {
        int n0 = wave * 32 + a * 16 + quad * 4;
        *(floatx4*)(aggOut + (size_t)node * DIM + n0) = hsum[a] * 0.1f;
    }
}

// ---------------- attention combine (per node, one wave) ----------------
__device__ __forceinline__ float wsum64(float v) {
    #pragma unroll
    for (int off = 32; off > 0; off >>= 1) v += __shfl_xor(v, off, 64);
    return v;
}

__global__ __launch_bounds__(256) void att_kernel(
    const int* __restrict__ c_ids,
    const float* __restrict__ emb0, const float* __restrict__ emb1,
    const float* __restrict__ attW,
    const float* __restrict__ agg0, const float* __restrict__ agg1,
    float* __restrict__ outc, float* __restrict__ tbl1)
{
    const int wave = threadIdx.x >> 6, lane = threadIdx.x & 63;
    int gb = blockIdx.x;
    int group, node, Nn, ntype;
    const float* aggB; const float* emb;
    if (gb < NB / 4) { group = 0; node = gb * 4 + wave; ntype = 0; aggB = agg0; emb = emb0; Nn = NB; }
    else { group = 1; node = (gb - NB / 4) * 4 + wave; ntype = 1; aggB = agg1; emb = emb1; Nn = T1PAD; }
    int id = (group == 0) ? c_ids[node] : min(node, CN1 - 1);
    int d = lane * 2;
    float2 cur = *(const float2*)(emb + (size_t)id * DIM + d);

    #pragma unroll
    for (int l = 0; l < 2; l++) {
        float2 stk[3];
        #pragma unroll
        for (int k = 0; k < 3; k++)
            stk[k] = *(const float2*)(aggB + ((size_t)(l * 3 + k) * Nn + node) * DIM + d);
        const float* aw = attW + (l * 3 + ntype) * 2 * DIM;
        float2 ac = *(const float2*)(aw + d);
        float2 as = *(const float2*)(aw + DIM + d);
        float pc = ac.x * cur.x + ac.y * cur.y;
        float p0 = as.x * cur.x + as.y * cur.y;
        float p1 = as.x * stk[0].x + as.y * stk[0].y;
        float p2 = as.x * stk[1].x + as.y * stk[1].y;
        float p3 = as.x * stk[2].x + as.y * stk[2].y;
        float base = wsum64(pc);
        float s0 = base + wsum64(p0);
        float s1 = base + wsum64(p1);
        float s2 = base + wsum64(p2);
        float s3 = base + wsum64(p3);
        float mx = fmaxf(fmaxf(s0, s1), fmaxf(s2, s3));
        float e0 = __expf(s0 - mx), e1 = __expf(s1 - mx);
        float e2 = __expf(s2 - mx), e3 = __expf(s3 - mx);
        float rs = __builtin_amdgcn_rcpf(e0 + e1 + e2 + e3);
        float w0 = e0 * rs, w1 = e1 * rs, w2 = e2 * rs, w3 = e3 * rs;
        float nx = w0 * cur.x + w1 * stk[0].x + w2 * stk[1].x + w3 * stk[2].x;
        float ny = w0 * cur.y + w1 * stk[0].y + w2 * stk[1].y + w3 * stk[2].y;
        cur.x = nx > 0.f ? nx : 0.01f * nx;
        cur.y = ny > 0.f ? ny : 0.01f * ny;
    }
    float* dst = (group == 0) ? (outc + (size_t)node * DIM + d) : (tbl1 + (size_t)node * DIM + d);
    *(float2*)dst = cur;
}

// ---------------- gather pos/neg outputs from type-1 table ----------------
__global__ __launch_bounds__(256) void gather_kernel(
    const int* __restrict__ pos_ids, const int* __restrict__ neg_ids,
    const float* __restrict__ tbl1, float* __restrict__ outp, float* __restrict__ outn)
{
    int i = blockIdx.x * 256 + threadIdx.x;   // over 2 * NB * 32 float4s
    const int half = NB * 32;
    const int* ids; float* dst; int j = i;
    if (i < half) { ids = pos_ids; dst = outp; }
    else          { ids = neg_ids; dst = outn; j -= half; }
    int b = j >> 5, c = j & 31;
    int id = ids[b];
    ((floatx4*)dst)[j] = ((const floatx4*)tbl1)[(size_t)id * 32 + c];
}

extern "C" void kernel_launch(void* const* d_in, const int* in_sizes, int n_in,
                              void* d_out, int out_size, void* d_ws, size_t ws_size,
                              hipStream_t stream)
{
    const int* c_ids   = (const int*)d_in[0];
    const int* pos_ids = (const int*)d_in[1];
    const int* neg_ids = (const int*)d_in[2];
    const int* nb00 = (const int*)d_in[3];
    const int* nb01 = (const int*)d_in[4];
    const int* nb02 = (const int*)d_in[5];
    const int* nb10 = (const int*)d_in[6];
    const int* nb11 = (const int*)d_in[7];
    const int* nb12 = (const int*)d_in[8];
    const float* emb0 = (const float*)d_in[12];
    const float* emb1 = (const float*)d_in[13];
    const float* emb2 = (const float*)d_in[14];
    const float* rWih = (const float*)d_in[15];
    const float* rWhh = (const float*)d_in[16];
    const float* rbih = (const float*)d_in[17];
    const float* rbhh = (const float*)d_in[18];
    const float* attW = (const float*)d_in[19];

    char* ws = (char*)d_ws;
    _Float16* he0  = (_Float16*)(ws + OFF_HE0);
    _Float16* he1  = (_Float16*)(ws + OFF_HE1);
    _Float16* he2  = (_Float16*)(ws + OFF_HE2);
    _Float16* hwih = (_Float16*)(ws + OFF_WIH);
    _Float16* hwhh = (_Float16*)(ws + OFF_WHH);
    float*    agg0 = (float*)(ws + OFF_AGG0);
    float*    agg1 = (float*)(ws + OFF_AGG1);
    float*    tbl1 = (float*)(ws + OFF_TBL1);

    float* out  = (float*)d_out;
    float* outc = out;
    float* outp = out + (size_t)NB * DIM;
    float* outn = out + (size_t)2 * NB * DIM;

    // 1) fp16 conversion of embeddings + weights
    {
        int total4 = (CN0 + CN1 + CN2) * DIM / 4 + 2 * (2 * 3 * DIM * DIM / 4);
        int blocks = (total4 + 255) / 256;
        prep_kernel<<<blocks, 256, 0, stream>>>(emb0, emb1, emb2, rWih, rWhh,
                                                he0, he1, he2, hwih, hwhh);
    }
    // 2) RNN-mean aggregations: c batch (4096 nodes) + full type-1 table (2048)
    {
        dim3 grid(NB / GMT + T1PAD / GMT, 6);
        rnn_kernel<<<grid, 256, 0, stream>>>(c_ids, nb00, nb01, nb02, nb10, nb11, nb12,
                                             he0, he1, he2, hwih, hwhh, rbih, rbhh,
                                             agg0, agg1);
    }
    // 3) attention combine
    {
        int blocks = NB / 4 + T1PAD / 4;
        att_kernel<<<blocks, 256, 0, stream>>>(c_ids, emb0, emb1, attW, agg0, agg1,
                                               outc, tbl1);
    }
    // 4) gather pos/neg outputs
    {
        int blocks = 2 * NB * 32 / 256;
        gather_kernel<<<blocks, 256, 0, stream>>>(pos_ids, neg_ids, tbl1, outp, outn);
    }
}